// Round 8
// baseline (185.218 us; speedup 1.0000x reference)
//
#include <hip/hip_runtime.h>

// WindowedNorm: 47x47 box-window mean/var normalization, zero-padded,
// count_include_pad=False, Bessel-corrected. NHWC fp32 [B,224,224,3].
//
// One (batch, 14-row band) per block, processed as 7 sequential 2-row
// sub-bands reusing one 10.8KB LDS buffer -> 8 blocks/CU = 32 waves/CU
// (100% nominal occupancy; grid 2048 = exactly 8 resident per CU).
// Vertical running sums persist in registers across sub-bands (47-row
// init paid once per 14 output rows).
// Thread t (t<224) owns pixel-column w=t, all 3 channels (float3 ops).
//   Phase V (per sub-band): publish float2(S,Q) to vsq[r*3+c][w] for 2
//            rows, stash own-row x in 6 registers, slide the 47-row
//            window (add h+24 / sub h-23, float3 loads).
//   Phase P: 6 scan rows on 4 waves (2,2,1,1); per row: lane owns 4
//            consecutive w; 2 b128 reads, 6-level shfl scan, 2 b128
//            writes.
//   Phase N: window sum = P[w+23]-P[w-24]; lean var formula
//            var=(HQ-HS*mean)*rcp(n-1) (== Bessel-corrected form);
//            v_rcp via builtin; float3 coalesced store.

namespace {
constexpr int H = 224;
constexpr int W = 224;
constexpr int C = 3;
constexpr int WC = W * C;          // 672
constexpr int RAD = 23;            // window = 47
constexpr int SB = 2;              // rows per sub-band
constexpr int NSB = 7;             // sub-bands per block
constexpr int TH = SB * NSB;       // 14 rows per block (grid.x = 16)
constexpr int PADW = 226;          // float2/row; 226*8=1808B (16B mult.)
constexpr int NROWS = SB * C;      // 6 scan rows -> 10,848 B LDS
}

__global__ __launch_bounds__(256, 8) void wnorm_kernel(
    const float* __restrict__ in, float* __restrict__ out) {
  // 6 x 226 float2 = 10.8 KB -> 8 blocks/CU (32 waves/CU)
  __shared__ float2 vsq[NROWS][PADW];

  const int tid = threadIdx.x;
  const int lane = tid & 63;
  const int wv = tid >> 6;
  const int r0 = blockIdx.x * TH;
  const float* __restrict__ img = in + (size_t)blockIdx.y * (H * WC);
  float* __restrict__ oimg = out + (size_t)blockIdx.y * (H * WC);

  const bool own = (tid < W);
  const int w = tid;

  // ---- 47-row window init (once per 14 output rows) ----
  float S0 = 0.f, S1 = 0.f, S2 = 0.f, Q0 = 0.f, Q1 = 0.f, Q2 = 0.f;
  if (own) {
    const int rlo = r0 - RAD;
#pragma unroll 8
    for (int i = 0; i < 47; ++i) {
      const int r = rlo + i;
      const int rc = min(max(r, 0), H - 1);
      const float m = (r >= 0 && r < H) ? 1.f : 0.f;
      const float3 v = ((const float3*)(img + rc * WC))[w];
      const float x0 = v.x * m, x1 = v.y * m, x2 = v.z * m;
      S0 += x0; Q0 += x0 * x0;
      S1 += x1; Q1 += x1 * x1;
      S2 += x2; Q2 += x2 * x2;
    }
  }

  // per-thread horizontal window geometry (invariant across rows)
  const int hiw = min(w + RAD, W - 1);
  const int low = w - RAD - 1;               // exclusive left, may be <0
  const float cww = (float)(hiw - max(w - RAD, 0) + 1);

  float xr0[SB], xr1[SB], xr2[SB];           // own-row x stash (static idx)

  for (int sb = 0; sb < NSB; ++sb) {
    const int hb = r0 + sb * SB;

    // ---- Phase V: publish + x-stash + slide ----
#pragma unroll
    for (int r = 0; r < SB; ++r) {
      const int h = hb + r;
      if (own) {
        vsq[r * C + 0][w] = make_float2(S0, Q0);
        vsq[r * C + 1][w] = make_float2(S1, Q1);
        vsq[r * C + 2][w] = make_float2(S2, Q2);
        const float3 xv = ((const float3*)(img + h * WC))[w];
        xr0[r] = xv.x; xr1[r] = xv.y; xr2[r] = xv.z;
      }
      const int ra = h + RAD + 1;            // row entering
      const int rs = h - RAD;                // row leaving
      if (ra < H && own) {
        const float3 v = ((const float3*)(img + ra * WC))[w];
        S0 += v.x; Q0 += v.x * v.x;
        S1 += v.y; Q1 += v.y * v.y;
        S2 += v.z; Q2 += v.z * v.z;
      }
      if (rs >= 0 && own) {
        const float3 v = ((const float3*)(img + rs * WC))[w];
        S0 -= v.x; Q0 -= v.x * v.x;
        S1 -= v.y; Q1 -= v.y * v.y;
        S2 -= v.z; Q2 -= v.z * v.z;
      }
    }

    __syncthreads();

    // ---- Phase P: 6 scan rows on 4 waves (2,2,1,1) ----
    for (int rr = wv; rr < NROWS; rr += 4) {
      const bool act = (lane < 56);          // 56 lanes x 4 = 224
      const int w0 = lane << 2;
      float4* p4 = reinterpret_cast<float4*>(&vsq[rr][act ? w0 : 0]);
      float4 a = make_float4(0.f, 0.f, 0.f, 0.f), b = a;
      if (act) { a = p4[0]; b = p4[1]; }
      const float p0x = a.x,       p0y = a.y;
      const float p1x = p0x + a.z, p1y = p0y + a.w;
      const float p2x = p1x + b.x, p2y = p1y + b.y;
      const float p3x = p2x + b.z, p3y = p2y + b.w;
      float Tx = p3x, Ty = p3y;
#pragma unroll
      for (int d = 1; d < 64; d <<= 1) {
        const float sx = __shfl_up(Tx, d);
        const float sy = __shfl_up(Ty, d);
        if (lane >= d) { Tx += sx; Ty += sy; }
      }
      const float ex = Tx - p3x, ey = Ty - p3y;  // exclusive-before-lane
      if (act) {
        p4[0] = make_float4(p0x + ex, p0y + ey, p1x + ex, p1y + ey);
        p4[1] = make_float4(p2x + ex, p2y + ey, p3x + ex, p3y + ey);
      }
    }

    __syncthreads();

    // ---- Phase N: normalize + coalesced store ----
    if (own) {
#pragma unroll
      for (int r = 0; r < SB; ++r) {
        const int h = hb + r;
        const float chh =
            (float)(min(h + RAD, H - 1) - max(h - RAD, 0) + 1);
        const float n = chh * cww;
        const float inv = __builtin_amdgcn_rcpf(n);         // 1/n
        const float i1 = __builtin_amdgcn_rcpf(n - 1.0f);   // 1/(n-1)
        const float xc[3] = {xr0[r], xr1[r], xr2[r]};
        float o[3];
#pragma unroll
        for (int c = 0; c < C; ++c) {
          const float2 Ph = vsq[r * C + c][hiw];
          const float2 Pl = (low >= 0) ? vsq[r * C + c][low]
                                       : make_float2(0.f, 0.f);
          const float HS = Ph.x - Pl.x;
          const float HQ = Ph.y - Pl.y;
          const float mean = HS * inv;
          // (HQ - HS*mean)/(n-1) == Bessel-corrected variance
          float var = (HQ - HS * mean) * i1;
          var = fmaxf(var, 0.0f);
          o[c] = (xc[c] - mean) * rsqrtf(var + 1e-6f);
        }
        ((float3*)(oimg + h * WC))[w] = make_float3(o[0], o[1], o[2]);
      }
    }

    __syncthreads();   // protect vsq before next sub-band's publish
  }
}

extern "C" void kernel_launch(void* const* d_in, const int* in_sizes, int n_in,
                              void* d_out, int out_size, void* d_ws, size_t ws_size,
                              hipStream_t stream) {
  const float* in = (const float*)d_in[0];
  float* out = (float*)d_out;
  const int B = in_sizes[0] / (H * W * C);   // 128
  dim3 grid(H / TH, B);                      // 16 x 128 = 2048 blocks
  wnorm_kernel<<<grid, 256, 0, stream>>>(in, out);
}

// Round 9
// 166.153 us; speedup vs baseline: 1.1147x; 1.1147x over previous
//
#include <hip/hip_runtime.h>

// WindowedNorm: 47x47 box-window mean/var normalization, zero-padded,
// count_include_pad=False, Bessel-corrected. NHWC fp32 [B,224,224,3].
//
// Streaming-quarter design (R9): one block = one image QUARTER (56 rows x
// full width). 704 threads; thread t<672 owns one col-channel (c=t%3,
// w=t/3 -> global loads/stores perfectly coalesced at h*672+t).
// Vertical running (S,Q) stream down 56 rows in registers; the 47-row
// init is paid once per 56 rows (3.8 requested floats/elem vs 5.9 in R8).
// Re-read gap (sub-slide at +23 rows, x at +-24) ~6.5us < L2 lifetime ->
// slide/x re-reads hit L2, cutting the 3.2 TB/s fill-rate bottleneck's
// byte count. XCD swizzle co-locates each image's quarters on one XCD.
// Per 7-row group: publish (S,Q)->LDS, barrier, scan 21 rows on 11 waves,
// barrier, normalize+store, barrier. 38KB LDS -> 2 blocks/CU (22 waves).

namespace {
constexpr int H = 224;
constexpr int W = 224;
constexpr int C = 3;
constexpr int WC = W * C;          // 672
constexpr int RAD = 23;            // window = 47
constexpr int QH = 56;             // quarter height (4 quarters/image)
constexpr int G = 7;               // rows per group
constexpr int NG = QH / G;         // 8 groups
constexpr int NT = 704;            // threads (11 waves; 672 active)
constexpr int PADW = 226;          // float2/row; 226*8=1808B (16B mult.)
}

__global__ __launch_bounds__(NT, 6) void wnorm_kernel(
    const float* __restrict__ in, float* __restrict__ out) {
  // 7 x 3 x 226 float2 = 37.97 KB -> 2 blocks/CU (22 waves/CU)
  __shared__ float2 vsq[G][C][PADW];

  const int tid = threadIdx.x;
  const int lane = tid & 63;
  const int wv = tid >> 6;

  // bijective XCD swizzle: consecutive work items (quarters of the same
  // image, then consecutive images) land on the same XCD's chunk.
  const int nwg = gridDim.x;                 // 512 (divisible by 8)
  const int chunk = nwg >> 3;
  const int bid = blockIdx.x;
  const int work = (bid & 7) * chunk + (bid >> 3);
  const int img = work >> 2;                 // image 0..127
  const int q = work & 3;                    // quarter 0..3
  const int r0 = q * QH;

  const float* __restrict__ src = in + (size_t)img * (H * WC);
  float* __restrict__ dst = out + (size_t)img * (H * WC);

  const bool own = (tid < WC);
  const int col = tid;                       // element index within a row
  const int w = col / 3;
  const int c = col - 3 * w;

  // ---- 47-row window init (centered at output row r0) ----
  float S = 0.f, Q = 0.f;
  if (own) {
    if (r0 == 0) {                           // only quarter 0 needs masking
#pragma unroll 8
      for (int i = 0; i < 47; ++i) {
        const int r = i - RAD;
        const int rc = max(r, 0);
        const float m = (r >= 0) ? 1.f : 0.f;
        const float x = src[rc * WC + col] * m;
        S += x; Q += x * x;
      }
    } else {                                 // rows r0-23..r0+23 all valid
#pragma unroll 8
      for (int i = 0; i < 47; ++i) {
        const float x = src[(r0 - RAD + i) * WC + col];
        S += x; Q += x * x;
      }
    }
  }

  // per-thread horizontal window geometry (invariant across rows)
  const int hiw = min(w + RAD, W - 1);
  const int low = w - RAD - 1;               // exclusive left, may be <0
  const float cww = (float)(hiw - max(w - RAD, 0) + 1);

  for (int g = 0; g < NG; ++g) {
    const int h0 = r0 + g * G;

    // ---- batched loads for the group (add / sub / x streams) ----
    float xa[G], xs[G], xx[G];
    if (own) {
#pragma unroll
      for (int r = 0; r < G; ++r) {
        const int h = h0 + r;
        const int ra = h + RAD + 1;          // row entering the window
        const int rs = h - RAD;              // row leaving the window
        const float ma = (ra < H) ? 1.f : 0.f;
        const float ms = (rs >= 0) ? 1.f : 0.f;
        xa[r] = src[min(ra, H - 1) * WC + col] * ma;
        xs[r] = src[max(rs, 0) * WC + col] * ms;
        xx[r] = src[h * WC + col];
      }
      // ---- publish + slide (pure regs + LDS writes) ----
#pragma unroll
      for (int r = 0; r < G; ++r) {
        vsq[r][c][w] = make_float2(S, Q);
        S += xa[r]; Q += xa[r] * xa[r];
        S -= xs[r]; Q -= xs[r] * xs[r];
      }
    }

    __syncthreads();

    // ---- scan: 21 (row,ch) LDS rows on 11 waves ----
    for (int rr = wv; rr < G * C; rr += 11) {
      const int sr = rr / 3, sc = rr - 3 * (rr / 3);
      const bool act = (lane < 56);          // 56 lanes x 4 = 224
      const int w0 = lane << 2;
      float4* p4 = reinterpret_cast<float4*>(&vsq[sr][sc][act ? w0 : 0]);
      float4 a = make_float4(0.f, 0.f, 0.f, 0.f), b = a;
      if (act) { a = p4[0]; b = p4[1]; }
      const float p0x = a.x,       p0y = a.y;
      const float p1x = p0x + a.z, p1y = p0y + a.w;
      const float p2x = p1x + b.x, p2y = p1y + b.y;
      const float p3x = p2x + b.z, p3y = p2y + b.w;
      float Tx = p3x, Ty = p3y;
#pragma unroll
      for (int d = 1; d < 64; d <<= 1) {
        const float sx = __shfl_up(Tx, d);
        const float sy = __shfl_up(Ty, d);
        if (lane >= d) { Tx += sx; Ty += sy; }
      }
      const float ex = Tx - p3x, ey = Ty - p3y;  // exclusive-before-lane
      if (act) {
        p4[0] = make_float4(p0x + ex, p0y + ey, p1x + ex, p1y + ey);
        p4[1] = make_float4(p2x + ex, p2y + ey, p3x + ex, p3y + ey);
      }
    }

    __syncthreads();

    // ---- normalize + coalesced store ----
    if (own) {
#pragma unroll
      for (int r = 0; r < G; ++r) {
        const int h = h0 + r;
        const float chh =
            (float)(min(h + RAD, H - 1) - max(h - RAD, 0) + 1);
        const float n = chh * cww;
        const float inv = __builtin_amdgcn_rcpf(n);         // 1/n
        const float i1 = __builtin_amdgcn_rcpf(n - 1.0f);   // 1/(n-1)
        const float2 Ph = vsq[r][c][hiw];
        const float2 Pl = (low >= 0) ? vsq[r][c][low]
                                     : make_float2(0.f, 0.f);
        const float HS = Ph.x - Pl.x;
        const float HQ = Ph.y - Pl.y;
        const float mean = HS * inv;
        // (HQ - HS*mean)/(n-1) == Bessel-corrected variance
        float var = (HQ - HS * mean) * i1;
        var = fmaxf(var, 0.0f);
        dst[h * WC + col] = (xx[r] - mean) * rsqrtf(var + 1e-6f);
      }
    }

    __syncthreads();   // protect vsq before next group's publish
  }
}

extern "C" void kernel_launch(void* const* d_in, const int* in_sizes, int n_in,
                              void* d_out, int out_size, void* d_ws, size_t ws_size,
                              hipStream_t stream) {
  const float* in = (const float*)d_in[0];
  float* out = (float*)d_out;
  const int B = in_sizes[0] / (H * W * C);   // 128
  const int nwg = B * 4;                     // 512 quarter-blocks
  wnorm_kernel<<<dim3(nwg), dim3(NT), 0, stream>>>(in, out);
}